// Round 6
// baseline (43.806 us; speedup 1.0000x reference)
//
#include <hip/hip_runtime.h>
#include <stdint.h>

#define RS     1280          // input row stride in f32 elements = 16*80
#define SEGLEN 512
#define HDIM   80
#define NIT    8
// fold 1/sqrt(80) * log2(e) into Q so softmax runs in exp2 domain
#define QSC    (0.11180339887498949f * 1.4426950408889634f)

typedef __attribute__((ext_vector_type(8))) short short8;
typedef __attribute__((ext_vector_type(4))) float f32x4;

// f32 -> bf16 (round-half-up)
__device__ __forceinline__ uint32_t bfr(float x) {
    return (__builtin_bit_cast(uint32_t, x) + 0x8000u) >> 16;
}

__device__ __forceinline__ short8 mk8(uint32_t a, uint32_t b, uint32_t c, uint32_t d) {
    union { uint32_t u[4]; short8 s; } t;
    t.u[0] = a; t.u[1] = b; t.u[2] = c; t.u[3] = d;
    return t.s;
}

__device__ __forceinline__ void glds16(const void* g, void* l) {
    __builtin_amdgcn_global_load_lds(
        (const __attribute__((address_space(1))) void*)g,
        (__attribute__((address_space(3))) void*)l, 16, 0, 0);
}

// ============================ prepass (v2: linear stores) ============================
// Same ws image semantics as before:
//   Kb image[b] = logical_K[b ^ (((r>>1)&7)<<4)], logical bytes >=160 are zero.
//   Vt image[d][b] = keypair L((b ^ ((d&7)<<4))/4), L = PV-fragment key permutation.
// All global STORES are linear & fully coalesced; the swizzle permutation is
// applied on the READ side (global gather for K, LDS gather for V).
// blockIdx mapping: bid = it*128 + h*8 + seg  ->  bid%8 == seg == main reader's XCD.
__global__ __launch_bounds__(256) void prepass2_kernel(
    const float* __restrict__ k, const float* __restrict__ v,
    char* __restrict__ kbt, char* __restrict__ vtt)
{
    __shared__ uint16_t vtile[64 * 80];
    const int tid = threadIdx.x;
    const int bid = blockIdx.x;
    const int seg = bid & 7;
    const int h   = (bid >> 3) & 15;
    const int it  = bid >> 7;            // 0..7
    const int sb  = seg * 8 + it;
    const int s0  = sb * 64;
    char* kblk = kbt + (size_t)(h * 64 + sb) * 16384;
    char* vblk = vtt + (size_t)(h * 64 + sb) * 10240;

    // ---- V rows -> LDS bf16 (coalesced float4 loads) ----
    #pragma unroll
    for (int i = 0; i < 5; ++i) {
        int idx = tid + i * 256;          // 0..1279 float4s (64 rows x 20)
        int r = idx / 20, c4 = idx - r * 20;
        float4 f = *reinterpret_cast<const float4*>(
            v + (size_t)(s0 + r) * RS + h * HDIM + c4 * 4);
        uint32_t lo = bfr(f.x) | (bfr(f.y) << 16);
        uint32_t hi = bfr(f.z) | (bfr(f.w) << 16);
        *reinterpret_cast<uint2*>(&vtile[r * 80 + c4 * 4]) = make_uint2(lo, hi);
    }

    // ---- K image: permuted-source gather, LINEAR dwordx4 stores ----
    // 64 rows x 16 granules(16B); wave covers 4 full 256B rows per iter.
    #pragma unroll
    for (int i = 0; i < 4; ++i) {
        int idx = tid + i * 256;          // 0..1023
        int r   = idx >> 4;
        int g   = idx & 15;
        uint32_t swz  = (uint32_t)(((r >> 1) & 7) << 4);
        uint32_t bsrc = ((uint32_t)(g * 16)) ^ swz;    // logical byte of this granule
        uint32_t od0 = 0, od1 = 0, od2 = 0, od3 = 0;
        if (bsrc < 160) {                 // logical bytes >=160 are the zero pad
            const float* src = k + (size_t)(s0 + r) * RS + h * HDIM + (bsrc >> 1);
            float4 f0 = *reinterpret_cast<const float4*>(src);
            float4 f1 = *reinterpret_cast<const float4*>(src + 4);
            od0 = bfr(f0.x) | (bfr(f0.y) << 16);
            od1 = bfr(f0.z) | (bfr(f0.w) << 16);
            od2 = bfr(f1.x) | (bfr(f1.y) << 16);
            od3 = bfr(f1.z) | (bfr(f1.w) << 16);
        }
        uint4 st; st.x = od0; st.y = od1; st.z = od2; st.w = od3;
        *reinterpret_cast<uint4*>(kblk + r * 256 + g * 16) = st;
    }

    __syncthreads();

    // ---- V image: transposed+permuted LDS gather, LINEAR dwordx2 stores ----
    // 80 d-rows x 16 tasks(8B); wave covers 4 full 128B rows per iter.
    #pragma unroll
    for (int i = 0; i < 5; ++i) {
        int idx = tid + i * 256;          // 0..1279
        int d   = idx >> 4;               // 0..79
        int t8  = idx & 15;
        uint32_t vswz = (uint32_t)((d & 7) << 4);
        uint32_t bsrc = ((uint32_t)(t8 * 8)) ^ vswz;   // [0,128)
        int k2 = (int)(bsrc >> 2);
        uint32_t w01[2];
        #pragma unroll
        for (int j2 = 0; j2 < 2; ++j2) {
            int kk  = k2 + j2;
            int kc  = kk >> 4, q4p = (kk >> 2) & 3, jj = (kk & 3) * 2;
            int L   = (2 * kc + (jj >> 2)) * 16 + q4p * 4 + (jj & 3);
            uint32_t lo = vtile[L * 80 + d];
            uint32_t hi = vtile[(L + 1) * 80 + d];
            w01[j2] = lo | (hi << 16);
        }
        *reinterpret_cast<uint2*>(vblk + d * 128 + t8 * 8) = make_uint2(w01[0], w01[1]);
    }
}

// ============================ main attention (identical to R5) ============================
// double-buffered: [K(16384) V(10240)] x2
#define LDS_K0  0
#define LDS_V0  16384
#define LDS_K1  26624
#define LDS_V1  43008
#define LDS_SZ  53248

__global__ __launch_bounds__(256) void attn_v6_kernel(
    const float* __restrict__ q, const char* __restrict__ kbt,
    const char* __restrict__ vtt, float* __restrict__ out)
{
    __shared__ __align__(128) char lds[LDS_SZ];
    const int tid  = threadIdx.x;
    const int wave = __builtin_amdgcn_readfirstlane(tid >> 6);
    const int lane = tid & 63;
    const int r16  = lane & 15, q4 = lane >> 4;
    const int bid  = blockIdx.x;
    const int hs   = bid & 127, qt = bid >> 7;   // 4 blocks sharing (h,seg) are 128 apart
    const int h    = hs >> 3, seg = hs & 7;
    const int q0   = seg * SEGLEN + qt * 128;

    const char* kb = kbt + (size_t)(h * 64 + seg * 8) * 16384;
    const char* vb = vtt + (size_t)(h * 64 + seg * 8) * 10240;
    const int lo16 = lane * 16;

    // stage one (K,V) tile pair: 26 chunks of 1024B split across 4 waves
    // waves 0,1 issue 7 glds; waves 2,3 issue 6.
    auto STAGE = [&](const char* ks, const char* vs, char* kd, char* vd) {
        #pragma unroll
        for (int i = 0; i < 7; ++i) {
            int idx = wave + i * 4;
            if (idx < 16)      glds16(ks + idx * 1024 + lo16, kd + idx * 1024);
            else if (idx < 26) glds16(vs + (idx - 16) * 1024 + lo16, vd + (idx - 16) * 1024);
        }
    };

    // prologue: stage tile 0 into buffer 0 (no drain -- covered by iter-0 wait)
    STAGE(kb, vb, lds + LDS_K0, lds + LDS_V0);

    // Q fragments for 2 q-groups of 16 rows each (wave owns 32 q-rows).
    // kc=2, q4>=2 -> logical d 80..95 where K is zero-padded: load dummy d=0.
    short8 qf[2][3];
    #pragma unroll
    for (int g = 0; g < 2; ++g) {
        const float* qrow = q + (size_t)(q0 + wave * 32 + g * 16 + r16) * RS + h * HDIM;
        #pragma unroll
        for (int kc = 0; kc < 3; ++kc) {
            int d = kc * 32 + q4 * 8;
            if (kc == 2 && q4 >= 2) d = 0;
            float4 f0 = *reinterpret_cast<const float4*>(qrow + d);
            float4 f1 = *reinterpret_cast<const float4*>(qrow + d + 4);
            uint32_t w0 = bfr(f0.x * QSC) | (bfr(f0.y * QSC) << 16);
            uint32_t w1 = bfr(f0.z * QSC) | (bfr(f0.w * QSC) << 16);
            uint32_t w2 = bfr(f1.x * QSC) | (bfr(f1.y * QSC) << 16);
            uint32_t w3 = bfr(f1.z * QSC) | (bfr(f1.w * QSC) << 16);
            qf[g][kc] = mk8(w0, w1, w2, w3);
        }
    }

    float lsum[2] = {0.f, 0.f};
    f32x4 acc[2][5];
    #pragma unroll
    for (int g = 0; g < 2; ++g)
        #pragma unroll
        for (int dt = 0; dt < 5; ++dt) acc[g][dt] = f32x4{0.f, 0.f, 0.f, 0.f};

    for (int it = 0; it < NIT; ++it) {
        const int cur = it & 1;
        if (it < NIT - 1) {
            STAGE(kb + (it + 1) * 16384, vb + (it + 1) * 10240,
                  lds + (cur ? LDS_K0 : LDS_K1), lds + (cur ? LDS_V0 : LDS_V1));
            if (wave < 2) asm volatile("s_waitcnt vmcnt(7)" ::: "memory");
            else          asm volatile("s_waitcnt vmcnt(6)" ::: "memory");
        } else {
            asm volatile("s_waitcnt vmcnt(0)" ::: "memory");
        }
        __builtin_amdgcn_s_barrier();          // all waves' tile-it chunks landed
        __builtin_amdgcn_sched_barrier(0);     // pin: no LDS read hoisted above

        const char* kl = lds + (cur ? LDS_K1 : LDS_K0);
        const char* vl = lds + (cur ? LDS_V1 : LDS_V0);

        // ---- QK^T (swapped): s4[g][t][rg] = S[key=16t+4q4+rg][q=r16] ----
        f32x4 s4[2][4];
        #pragma unroll
        for (int g = 0; g < 2; ++g)
            #pragma unroll
            for (int t = 0; t < 4; ++t) s4[g][t] = f32x4{0.f, 0.f, 0.f, 0.f};
        __builtin_amdgcn_s_setprio(1);
        #pragma unroll
        for (int t = 0; t < 4; ++t) {
            int krow = t * 16 + r16;
            uint32_t rb = (uint32_t)(krow * 256);
            uint32_t swz = (uint32_t)(((krow >> 1) & 7) << 4);
            #pragma unroll
            for (int kc = 0; kc < 3; ++kc) {
                short8 kf = *reinterpret_cast<const short8*>(
                    kl + rb + (((uint32_t)(kc * 64 + q4 * 16)) ^ swz));
                s4[0][t] = __builtin_amdgcn_mfma_f32_16x16x32_bf16(kf, qf[0][kc], s4[0][t], 0, 0, 0);
                s4[1][t] = __builtin_amdgcn_mfma_f32_16x16x32_bf16(kf, qf[1][kc], s4[1][t], 0, 0, 0);
            }
        }
        __builtin_amdgcn_s_setprio(0);

        // ---- max-free softmax: p = exp2(s), pack to bf16 pairs ----
        uint32_t pb[2][4][2];
        #pragma unroll
        for (int g = 0; g < 2; ++g) {
            #pragma unroll
            for (int t = 0; t < 4; ++t) {
                float p0 = exp2f(s4[g][t][0]);
                float p1 = exp2f(s4[g][t][1]);
                float p2 = exp2f(s4[g][t][2]);
                float p3 = exp2f(s4[g][t][3]);
                lsum[g] += (p0 + p1) + (p2 + p3);
                uint32_t d0, d1;
                asm("v_cvt_pk_bf16_f32 %0, %1, %2" : "=v"(d0) : "v"(p0), "v"(p1));
                asm("v_cvt_pk_bf16_f32 %0, %1, %2" : "=v"(d1) : "v"(p2), "v"(p3));
                pb[g][t][0] = d0; pb[g][t][1] = d1;
            }
        }

        // ---- PV A=Vt (O^T), B=P: zero-shuffle fragments (key-permuted Vt) ----
        short8 af[2][2];
        #pragma unroll
        for (int g = 0; g < 2; ++g) {
            af[g][0] = mk8(pb[g][0][0], pb[g][0][1], pb[g][1][0], pb[g][1][1]);
            af[g][1] = mk8(pb[g][2][0], pb[g][2][1], pb[g][3][0], pb[g][3][1]);
        }
        __builtin_amdgcn_s_setprio(1);
        #pragma unroll
        for (int dt = 0; dt < 5; ++dt) {
            int drow = dt * 16 + r16;
            uint32_t vr = (uint32_t)(drow * 128);
            uint32_t vswz = (uint32_t)((drow & 7) << 4);
            short8 vf0 = *reinterpret_cast<const short8*>(
                vl + vr + (((uint32_t)(q4 * 16)) ^ vswz));
            acc[0][dt] = __builtin_amdgcn_mfma_f32_16x16x32_bf16(vf0, af[0][0], acc[0][dt], 0, 0, 0);
            acc[1][dt] = __builtin_amdgcn_mfma_f32_16x16x32_bf16(vf0, af[1][0], acc[1][dt], 0, 0, 0);
            short8 vf1 = *reinterpret_cast<const short8*>(
                vl + vr + (((uint32_t)(64 + q4 * 16)) ^ vswz));
            acc[0][dt] = __builtin_amdgcn_mfma_f32_16x16x32_bf16(vf1, af[0][1], acc[0][dt], 0, 0, 0);
            acc[1][dt] = __builtin_amdgcn_mfma_f32_16x16x32_bf16(vf1, af[1][1], acc[1][dt], 0, 0, 0);
        }
        __builtin_amdgcn_s_setprio(0);

        if (it < NIT - 1) __builtin_amdgcn_s_barrier();  // WAR: done reading buf[cur]
    }

    // ---- epilogue: O^T layout -> lane owns q-row r16; float4 stores ----
    #pragma unroll
    for (int g = 0; g < 2; ++g) {
        float l = lsum[g];
        l += __shfl_xor(l, 16);
        l += __shfl_xor(l, 32);
        float inv = 1.0f / l;
        int qrow = q0 + wave * 32 + g * 16 + r16;
        float* op = out + (size_t)qrow * RS + h * HDIM + q4 * 4;
        #pragma unroll
        for (int dt = 0; dt < 5; ++dt) {
            float4 st;
            st.x = acc[g][dt][0] * inv;
            st.y = acc[g][dt][1] * inv;
            st.z = acc[g][dt][2] * inv;
            st.w = acc[g][dt][3] * inv;
            *reinterpret_cast<float4*>(op + dt * 16) = st;
        }
    }
}

// ===================== round-1 fallback (ws too small) =====================
#define FB_LDS_Q     0
#define FB_LDS_K     12288
#define FB_LDS_P     24576
#define FB_LDS_BYTES 32768
#define FB_SCALE     0.11180339887498949f

__device__ __forceinline__ void fb_stage64(char* lds, const float* __restrict__ g,
                                           int dstOff, float scale, int tid) {
    #pragma unroll
    for (int i = 0; i < 5; ++i) {
        int idx = tid + i * 256;
        int r   = idx / 20;
        int c4  = idx - r * 20;
        const float4 val = *reinterpret_cast<const float4*>(g + (size_t)r * RS + c4 * 4);
        uint32_t lo = bfr(val.x * scale) | (bfr(val.y * scale) << 16);
        uint32_t hi = bfr(val.z * scale) | (bfr(val.w * scale) << 16);
        uint32_t a = (uint32_t)(dstOff + r * 192 + c4 * 8);
        a ^= (uint32_t)((r & 7) << 4);
        *reinterpret_cast<uint2*>(lds + a) = make_uint2(lo, hi);
    }
}

__global__ __launch_bounds__(256) void attn_seg_kernel(
    const float* __restrict__ q, const float* __restrict__ k,
    const float* __restrict__ v, float* __restrict__ out)
{
    __shared__ __align__(128) char lds[FB_LDS_BYTES];
    const int tid  = threadIdx.x;
    const int wave = tid >> 6;
    const int lane = tid & 63;
    const int r16  = lane & 15;
    const int q4   = lane >> 4;
    const int bid = blockIdx.x;
    const int hs  = bid & 127;
    const int qt  = bid >> 7;
    const int h   = hs >> 3;
    const int seg = hs & 7;
    const int q0  = seg * SEGLEN + qt * 64;
    {
        uint32_t* w = reinterpret_cast<uint32_t*>(lds);
        #pragma unroll
        for (int i = 0; i < 24; ++i) w[tid + i * 256] = 0u;
    }
    __syncthreads();
    fb_stage64(lds, q + (size_t)q0 * RS + h * HDIM, FB_LDS_Q, FB_SCALE, tid);
    __syncthreads();
    short8 qf[3];
    {
        int row = wave * 16 + r16;
        #pragma unroll
        for (int kc = 0; kc < 3; ++kc) {
            uint32_t a = (uint32_t)(FB_LDS_Q + row * 192 + kc * 64 + q4 * 16);
            a ^= (uint32_t)((row & 7) << 4);
            qf[kc] = *reinterpret_cast<const short8*>(lds + a);
        }
    }
    float mrun[4], lsum[4];
    f32x4 acc[5];
    #pragma unroll
    for (int rg = 0; rg < 4; ++rg) { mrun[rg] = -1e30f; lsum[rg] = 0.f; }
    #pragma unroll
    for (int dt = 0; dt < 5; ++dt) acc[dt] = f32x4{0.f, 0.f, 0.f, 0.f};
    const uint32_t pbase = (uint32_t)(FB_LDS_P + wave * 2048);
    for (int it = 0; it < SEGLEN / 64; ++it) {
        const int kv0 = seg * SEGLEN + it * 64;
        if (it) __syncthreads();
        fb_stage64(lds, k + (size_t)kv0 * RS + h * HDIM, FB_LDS_K, 1.f, tid);
        __syncthreads();
        f32x4 s[4];
        #pragma unroll
        for (int t = 0; t < 4; ++t) s[t] = f32x4{0.f, 0.f, 0.f, 0.f};
        #pragma unroll
        for (int t = 0; t < 4; ++t) {
            int krow = t * 16 + r16;
            #pragma unroll
            for (int kc = 0; kc < 3; ++kc) {
                uint32_t a = (uint32_t)(FB_LDS_K + krow * 192 + kc * 64 + q4 * 16);
                a ^= (uint32_t)((krow & 7) << 4);
                short8 kf = *reinterpret_cast<const short8*>(lds + a);
                s[t] = __builtin_amdgcn_mfma_f32_16x16x32_bf16(qf[kc], kf, s[t], 0, 0, 0);
            }
        }
        float mnew[4], corr[4], psum[4];
        #pragma unroll
        for (int rg = 0; rg < 4; ++rg) {
            float mx = fmaxf(fmaxf(s[0][rg], s[1][rg]), fmaxf(s[2][rg], s[3][rg]));
            mx = fmaxf(mx, __shfl_xor(mx, 1));
            mx = fmaxf(mx, __shfl_xor(mx, 2));
            mx = fmaxf(mx, __shfl_xor(mx, 4));
            mx = fmaxf(mx, __shfl_xor(mx, 8));
            mnew[rg] = fmaxf(mrun[rg], mx);
            corr[rg] = __expf(mrun[rg] - mnew[rg]);
            mrun[rg] = mnew[rg];
            lsum[rg] *= corr[rg];
            psum[rg] = 0.f;
        }
        #pragma unroll
        for (int dt = 0; dt < 5; ++dt)
            #pragma unroll
            for (int rg = 0; rg < 4; ++rg) acc[dt][rg] *= corr[rg];
        #pragma unroll
        for (int t = 0; t < 4; ++t) {
            #pragma unroll
            for (int rg = 0; rg < 4; ++rg) {
                float p = __expf(s[t][rg] - mnew[rg]);
                psum[rg] += p;
                int prow = q4 * 4 + rg;
                uint32_t a = pbase + (uint32_t)(prow * 128 + (t * 16 + r16) * 2);
                a ^= (uint32_t)((prow & 7) << 4);
                *reinterpret_cast<uint16_t*>(lds + a) = (uint16_t)bfr(p);
            }
        }
        #pragma unroll
        for (int rg = 0; rg < 4; ++rg) {
            float ps = psum[rg];
            ps += __shfl_xor(ps, 1);
            ps += __shfl_xor(ps, 2);
            ps += __shfl_xor(ps, 4);
            ps += __shfl_xor(ps, 8);
            lsum[rg] += ps;
        }
        short8 pf[2];
        #pragma unroll
        for (int kc = 0; kc < 2; ++kc) {
            uint32_t a = pbase + (uint32_t)(r16 * 128 + kc * 64 + q4 * 16);
            a ^= (uint32_t)((r16 & 7) << 4);
            pf[kc] = *reinterpret_cast<const short8*>(lds + a);
        }
        const float* vb = v + (size_t)kv0 * RS + h * HDIM;
        #pragma unroll
        for (int kc = 0; kc < 2; ++kc) {
            #pragma unroll
            for (int dt = 0; dt < 5; ++dt) {
                int d = dt * 16 + r16;
                short8 vf;
                #pragma unroll
                for (int j = 0; j < 8; ++j) {
                    float f = vb[(size_t)(kc * 32 + q4 * 8 + j) * RS + d];
                    vf[j] = (short)bfr(f);
                }
                acc[dt] = __builtin_amdgcn_mfma_f32_16x16x32_bf16(pf[kc], vf, acc[dt], 0, 0, 0);
            }
        }
    }
    #pragma unroll
    for (int rg = 0; rg < 4; ++rg) {
        float inv = 1.0f / lsum[rg];
        int qrow = q0 + wave * 16 + q4 * 4 + rg;
        #pragma unroll
        for (int dt = 0; dt < 5; ++dt) {
            out[(size_t)qrow * RS + h * HDIM + dt * 16 + r16] = acc[dt][rg] * inv;
        }
    }
}

// ============================ launch ============================
extern "C" void kernel_launch(void* const* d_in, const int* in_sizes, int n_in,
                              void* d_out, int out_size, void* d_ws, size_t ws_size,
                              hipStream_t stream) {
    const float* q = (const float*)d_in[0];
    const float* k = (const float*)d_in[1];
    const float* v = (const float*)d_in[2];
    float* out = (float*)d_out;

    const size_t KB_BYTES = (size_t)16 * 64 * 16384;  // 16,777,216
    const size_t VT_BYTES = (size_t)16 * 64 * 10240;  // 10,485,760
    const size_t NEED = KB_BYTES + VT_BYTES;          // 27,262,976

    if (ws_size >= NEED) {
        char* kbt = (char*)d_ws;
        char* vtt = (char*)d_ws + KB_BYTES;
        prepass2_kernel<<<dim3(1024), dim3(256), 0, stream>>>(k, v, kbt, vtt);
        attn_v6_kernel<<<dim3(512), dim3(256), 0, stream>>>(q, kbt, vtt, out);
    } else {
        attn_seg_kernel<<<dim3(1024), dim3(256), 0, stream>>>(q, k, v, out);
    }
}

// Round 7
// 31.729 us; speedup vs baseline: 1.3806x; 1.3806x over previous
//
#include <hip/hip_runtime.h>
#include <stdint.h>

#define RS     1280          // input row stride in f32 elements = 16*80
#define SEGLEN 512
#define HDIM   80
#define NIT    8
// fold 1/sqrt(80) * log2(e) into Q so softmax runs in exp2 domain
#define QSC    (0.11180339887498949f * 1.4426950408889634f)

typedef __attribute__((ext_vector_type(8))) short short8;
typedef __attribute__((ext_vector_type(4))) float f32x4;

// f32 -> bf16 (round-half-up)
__device__ __forceinline__ uint32_t bfr(float x) {
    return (__builtin_bit_cast(uint32_t, x) + 0x8000u) >> 16;
}

__device__ __forceinline__ short8 mk8(uint32_t a, uint32_t b, uint32_t c, uint32_t d) {
    union { uint32_t u[4]; short8 s; } t;
    t.u[0] = a; t.u[1] = b; t.u[2] = c; t.u[3] = d;
    return t.s;
}

// ===================== fused attention (no prepass, no ws) =====================
// LDS images per KV tile (identical semantics to the verified R4-R6 layout):
//   K: row r (key 0..63) stride 256B; logical byte c stored at r*256 + (c ^ kswz(r)),
//      kswz(r) = ((r>>1)&7)<<4; logical bytes [160,192) are zero (pad), kept zero
//      by a one-time zero-init of the K regions (staging only writes c<160).
//   VT: row d (0..79) stride 128B; physical keypair slot kp stored at
//      d*128 + ((kp*4) ^ ((d&7)<<4)); slot kp holds logical keys L(2kp), L(2kp)+1,
//      L(s) = 16*(2*(s>>5) + ((s&7)>>2)) + 4*((s>>3)&3) + (s&3)  (PV-fragment perm).
#define LDS_K0  0
#define LDS_V0  16384
#define LDS_K1  26624
#define LDS_V1  43008
#define LDS_SZ  53248

__global__ __launch_bounds__(512) void attn_fused_kernel(
    const float* __restrict__ q, const float* __restrict__ k,
    const float* __restrict__ v, float* __restrict__ out)
{
    __shared__ __align__(128) char lds[LDS_SZ];
    const int tid  = threadIdx.x;
    const int wave = __builtin_amdgcn_readfirstlane(tid >> 6);
    const int lane = tid & 63;
    const int r16  = lane & 15, q4 = lane >> 4;
    const int bid  = blockIdx.x;               // 256 blocks = qhalf*128 + h*8 + seg
    const int seg  = bid & 7;                  // pair (qhalf 0/1) differs by 128 -> same XCD
    const int h    = (bid >> 3) & 15;
    const int qh   = bid >> 7;
    const int q0   = seg * SEGLEN + qh * 256;
    const int kv0  = seg * SEGLEN;

    // ---------- per-thread staging tasks (constant across iterations) ----------
    const int  stid = tid & 255;
    const bool isK  = (tid < 256);             // waves 0-3 stage K, waves 4-7 stage V

    // K tasks: 1280 float4 (64 rows x 20), 5 per thread
    int kGoff[5], kLoff[5];
    #pragma unroll
    for (int i = 0; i < 5; ++i) {
        int t  = stid + i * 256;
        int r  = t / 20, c4 = t - r * 20;
        kGoff[i] = r * RS + h * HDIM + c4 * 4;
        kLoff[i] = r * 256 + ((c4 * 8) ^ (((r >> 1) & 7) << 4));
    }
    // V tasks: 640 (keypair kp, c4), up to 3 per thread; loads rows L(2kp), L(2kp)+1
    int vGoff0[3], vGoff1[3], vKp[3], vC4[3];
    bool vOk[3];
    #pragma unroll
    for (int i = 0; i < 3; ++i) {
        int t  = stid + i * 256;
        vOk[i] = (t < 640);
        int kp = t & 31, c4 = t >> 5;
        int L  = 16 * (2 * (kp >> 4) + ((kp & 3) >> 1)) + 4 * ((kp >> 2) & 3) + 2 * (kp & 1);
        vKp[i] = kp; vC4[i] = c4;
        vGoff0[i] = L * RS + h * HDIM + c4 * 4;
        vGoff1[i] = vGoff0[i] + RS;
    }

    f32x4 kReg[5], vReg0[3], vReg1[3];

    auto LOAD = [&](int it) {
        const float* kbase = k + (size_t)(kv0 + it * 64) * RS;
        const float* vbase = v + (size_t)(kv0 + it * 64) * RS;
        if (isK) {
            #pragma unroll
            for (int i = 0; i < 5; ++i)
                kReg[i] = *reinterpret_cast<const f32x4*>(kbase + kGoff[i]);
        } else {
            #pragma unroll
            for (int i = 0; i < 3; ++i) if (vOk[i]) {
                vReg0[i] = *reinterpret_cast<const f32x4*>(vbase + vGoff0[i]);
                vReg1[i] = *reinterpret_cast<const f32x4*>(vbase + vGoff1[i]);
            }
        }
    };
    auto WRITE = [&](int buf) {
        char* kd = lds + (buf ? LDS_K1 : LDS_K0);
        char* vd = lds + (buf ? LDS_V1 : LDS_V0);
        if (isK) {
            #pragma unroll
            for (int i = 0; i < 5; ++i) {
                uint32_t lo = bfr(kReg[i][0]) | (bfr(kReg[i][1]) << 16);
                uint32_t hi = bfr(kReg[i][2]) | (bfr(kReg[i][3]) << 16);
                *reinterpret_cast<uint2*>(kd + kLoff[i]) = make_uint2(lo, hi);
            }
        } else {
            #pragma unroll
            for (int i = 0; i < 3; ++i) if (vOk[i]) {
                #pragma unroll
                for (int j = 0; j < 4; ++j) {
                    int d = vC4[i] * 4 + j;
                    uint32_t w = bfr(vReg0[i][j]) | (bfr(vReg1[i][j]) << 16);
                    *reinterpret_cast<uint32_t*>(
                        vd + d * 128 + ((vKp[i] * 4) ^ ((d & 7) << 4))) = w;
                }
            }
        }
    };

    // ---------- zero-init K regions (covers the zero pad bytes) ----------
    #pragma unroll
    for (int i = 0; i < 4; ++i) {
        *reinterpret_cast<uint2*>(lds + LDS_K0 + (tid + i * 512) * 8) = make_uint2(0u, 0u);
        *reinterpret_cast<uint2*>(lds + LDS_K1 + (tid + i * 512) * 8) = make_uint2(0u, 0u);
    }

    // issue tile-0 global loads early; Q fragment build overlaps their latency
    LOAD(0);

    // Q fragments: 2 groups of 16 q-rows (wave owns 32 rows).
    // kc=2, q4>=2 -> logical d 80..95 where K is zero-padded: load dummy d=0.
    short8 qf[2][3];
    #pragma unroll
    for (int g = 0; g < 2; ++g) {
        const float* qrow = q + (size_t)(q0 + wave * 32 + g * 16 + r16) * RS + h * HDIM;
        #pragma unroll
        for (int kc = 0; kc < 3; ++kc) {
            int d = kc * 32 + q4 * 8;
            if (kc == 2 && q4 >= 2) d = 0;
            f32x4 f0 = *reinterpret_cast<const f32x4*>(qrow + d);
            f32x4 f1 = *reinterpret_cast<const f32x4*>(qrow + d + 4);
            uint32_t w0 = bfr(f0[0] * QSC) | (bfr(f0[1] * QSC) << 16);
            uint32_t w1 = bfr(f0[2] * QSC) | (bfr(f0[3] * QSC) << 16);
            uint32_t w2 = bfr(f1[0] * QSC) | (bfr(f1[1] * QSC) << 16);
            uint32_t w3 = bfr(f1[2] * QSC) | (bfr(f1[3] * QSC) << 16);
            qf[g][kc] = mk8(w0, w1, w2, w3);
        }
    }

    float lsum[2] = {0.f, 0.f};
    f32x4 acc[2][5];
    #pragma unroll
    for (int g = 0; g < 2; ++g)
        #pragma unroll
        for (int dt = 0; dt < 5; ++dt) acc[g][dt] = f32x4{0.f, 0.f, 0.f, 0.f};

    __syncthreads();          // zero-init visible before any staging write
    WRITE(0);
    __syncthreads();          // tile 0 resident

    for (int it = 0; it < NIT; ++it) {
        const int cur = it & 1;
        if (it < NIT - 1) LOAD(it + 1);        // issue early; consumed after compute

        const char* kl = lds + (cur ? LDS_K1 : LDS_K0);
        const char* vl = lds + (cur ? LDS_V1 : LDS_V0);

        // ---- QK^T (swapped): s4[g][t][rg] = S[key=16t+4q4+rg][q=r16] ----
        f32x4 s4[2][4];
        #pragma unroll
        for (int g = 0; g < 2; ++g)
            #pragma unroll
            for (int t = 0; t < 4; ++t) s4[g][t] = f32x4{0.f, 0.f, 0.f, 0.f};
        __builtin_amdgcn_s_setprio(1);
        #pragma unroll
        for (int t = 0; t < 4; ++t) {
            int krow = t * 16 + r16;
            uint32_t rb  = (uint32_t)(krow * 256);
            uint32_t swz = (uint32_t)(((krow >> 1) & 7) << 4);
            #pragma unroll
            for (int kc = 0; kc < 3; ++kc) {
                short8 kf = *reinterpret_cast<const short8*>(
                    kl + rb + (((uint32_t)(kc * 64 + q4 * 16)) ^ swz));
                s4[0][t] = __builtin_amdgcn_mfma_f32_16x16x32_bf16(kf, qf[0][kc], s4[0][t], 0, 0, 0);
                s4[1][t] = __builtin_amdgcn_mfma_f32_16x16x32_bf16(kf, qf[1][kc], s4[1][t], 0, 0, 0);
            }
        }
        __builtin_amdgcn_s_setprio(0);

        // ---- max-free softmax: p = exp2(s), pack to bf16 pairs ----
        uint32_t pb[2][4][2];
        #pragma unroll
        for (int g = 0; g < 2; ++g) {
            #pragma unroll
            for (int t = 0; t < 4; ++t) {
                float p0 = exp2f(s4[g][t][0]);
                float p1 = exp2f(s4[g][t][1]);
                float p2 = exp2f(s4[g][t][2]);
                float p3 = exp2f(s4[g][t][3]);
                lsum[g] += (p0 + p1) + (p2 + p3);
                uint32_t d0, d1;
                asm("v_cvt_pk_bf16_f32 %0, %1, %2" : "=v"(d0) : "v"(p0), "v"(p1));
                asm("v_cvt_pk_bf16_f32 %0, %1, %2" : "=v"(d1) : "v"(p2), "v"(p3));
                pb[g][t][0] = d0; pb[g][t][1] = d1;
            }
        }

        // ---- PV A=Vt (O^T), B=P: zero-shuffle fragments (key-permuted Vt) ----
        short8 af[2][2];
        #pragma unroll
        for (int g = 0; g < 2; ++g) {
            af[g][0] = mk8(pb[g][0][0], pb[g][0][1], pb[g][1][0], pb[g][1][1]);
            af[g][1] = mk8(pb[g][2][0], pb[g][2][1], pb[g][3][0], pb[g][3][1]);
        }
        __builtin_amdgcn_s_setprio(1);
        #pragma unroll
        for (int dt = 0; dt < 5; ++dt) {
            int drow = dt * 16 + r16;
            uint32_t vr   = (uint32_t)(drow * 128);
            uint32_t vswz = (uint32_t)((drow & 7) << 4);
            short8 vf0 = *reinterpret_cast<const short8*>(
                vl + vr + (((uint32_t)(q4 * 16)) ^ vswz));
            acc[0][dt] = __builtin_amdgcn_mfma_f32_16x16x32_bf16(vf0, af[0][0], acc[0][dt], 0, 0, 0);
            acc[1][dt] = __builtin_amdgcn_mfma_f32_16x16x32_bf16(vf0, af[1][0], acc[1][dt], 0, 0, 0);
            short8 vf1 = *reinterpret_cast<const short8*>(
                vl + vr + (((uint32_t)(64 + q4 * 16)) ^ vswz));
            acc[0][dt] = __builtin_amdgcn_mfma_f32_16x16x32_bf16(vf1, af[0][1], acc[0][dt], 0, 0, 0);
            acc[1][dt] = __builtin_amdgcn_mfma_f32_16x16x32_bf16(vf1, af[1][1], acc[1][dt], 0, 0, 0);
        }
        __builtin_amdgcn_s_setprio(0);

        if (it < NIT - 1) {
            WRITE(cur ^ 1);        // compiler inserts the vmcnt wait here (T14)
            __syncthreads();       // next tile resident; all waves done with cur
        }
    }

    // ---- epilogue: O^T layout -> lane owns q-row r16; float4 stores ----
    #pragma unroll
    for (int g = 0; g < 2; ++g) {
        float l = lsum[g];
        l += __shfl_xor(l, 16);
        l += __shfl_xor(l, 32);
        float inv = 1.0f / l;
        int qrow = q0 + wave * 32 + g * 16 + r16;
        float* op = out + (size_t)qrow * RS + h * HDIM + q4 * 4;
        #pragma unroll
        for (int dt = 0; dt < 5; ++dt) {
            float4 st;
            st.x = acc[g][dt][0] * inv;
            st.y = acc[g][dt][1] * inv;
            st.z = acc[g][dt][2] * inv;
            st.w = acc[g][dt][3] * inv;
            *reinterpret_cast<float4*>(op + dt * 16) = st;
        }
    }
}

// ============================ launch ============================
extern "C" void kernel_launch(void* const* d_in, const int* in_sizes, int n_in,
                              void* d_out, int out_size, void* d_ws, size_t ws_size,
                              hipStream_t stream) {
    const float* q = (const float*)d_in[0];
    const float* k = (const float*)d_in[1];
    const float* v = (const float*)d_in[2];
    float* out = (float*)d_out;
    (void)d_ws; (void)ws_size;
    // 256 blocks = 2 q-halves x 16 heads x 8 segs; 512 threads (8 waves x 32 q-rows)
    attn_fused_kernel<<<dim3(256), dim3(512), 0, stream>>>(q, k, v, out);
}